// Round 6
// baseline (5622.143 us; speedup 1.0000x reference)
//
#include <hip/hip_runtime.h>
#include <hip/hip_bf16.h>

// ProductGraphsModel: 2x256 independent 5-layer GCN stacks + mean-pool + FC.
// Round 6:
//  - agg: wave-uniform scalar edge loads (s_load) + x8 unroll / 4 accs,
//    replacing vector-load+readlane (was ~14 VALU/edge -> ~4).
//  - packing K=768 [hi|lo|hi] -> K=512 [hi|lo]; GEMM walks a 24-step
//    (ak,bk) offset table to realize hi*hi + lo*hi + hi*lo.

#define G_   256
#define N_   512
#define E_   16384
#define ET_  (E_ + N_)   // edges + self-loops
#define H_   256
#define KP_  512         // packed K = 2*H ([hi|lo])
#define FIN  4
#define FG   6
#define C_   3
#define L_   5
#define B_   512   // 2*G_ instances (home then away)

typedef __attribute__((ext_vector_type(4))) float f32x4;
typedef __attribute__((ext_vector_type(8))) short bf16x8;

__device__ __forceinline__ void gload_lds16(const void* g, void* l) {
    __builtin_amdgcn_global_load_lds(
        (const __attribute__((address_space(1))) void*)g,
        (__attribute__((address_space(3))) void*)l, 16, 0, 0);
}

// m204 bijective chunked swizzle: orig%8 = HW XCD.
__device__ __forceinline__ int xcd_chunk_swizzle(int orig, int nwg) {
    const int q = nwg >> 3, r = nwg & 7, x = orig & 7;
    const int base = (x < r) ? x * (q + 1) : r * (q + 1) + (x - r) * q;
    return base + (orig >> 3);
}

// ---------------------------------------------------------------- prep ----
// CSR by dst with self-loop at slot rowptr[t] (val = dinv^2, col = t).
__global__ __launch_bounds__(256) void prep_kernel(
    const int* __restrict__ hei, const int* __restrict__ aei,
    const float* __restrict__ hew, const float* __restrict__ aew,
    int inst0,
    int* __restrict__ colv, float* __restrict__ valv, int* __restrict__ rowptr)
{
    const int ci = blockIdx.x;
    const int b  = inst0 + ci;
    const int g  = (b < G_) ? b : b - G_;
    const int*   ei = ((b < G_) ? hei : aei) + (size_t)g * 2 * E_;
    const float* ew = ((b < G_) ? hew : aew) + (size_t)g * E_;
    const int* srcA = ei;
    const int* dstA = ei + E_;

    __shared__ float degS[N_];
    __shared__ int   cntS[N_];
    __shared__ int   startS[N_ + 1];
    __shared__ int   curS[N_];
    const int tid = threadIdx.x;

    for (int n = tid; n < N_; n += 256) { degS[n] = 1.0f; cntS[n] = 0; }  // self weight 1
    __syncthreads();
    for (int e = tid; e < E_; e += 256) {
        atomicAdd(&degS[dstA[e]], ew[e]);
        atomicAdd(&cntS[dstA[e]], 1);
    }
    __syncthreads();
    for (int n = tid; n < N_; n += 256) degS[n] = rsqrtf(degS[n]);   // dinv
    __syncthreads();
    if (tid == 0) {
        int acc = 0;
        for (int n = 0; n < N_; ++n) { startS[n] = acc; acc += cntS[n] + 1; }
        startS[N_] = acc;    // = ET_
    }
    __syncthreads();
    for (int n = tid; n <= N_; n += 256) rowptr[(size_t)ci * (N_ + 1) + n] = startS[n];
    for (int n = tid; n < N_; n += 256) {
        curS[n] = 1;                                   // slot 0 = self loop
        colv[(size_t)ci * ET_ + startS[n]] = n;
        valv[(size_t)ci * ET_ + startS[n]] = degS[n] * degS[n];
    }
    __syncthreads();
    for (int e = tid; e < E_; e += 256) {
        int t = dstA[e], s = srcA[e];
        int pos = startS[t] + atomicAdd(&curS[t], 1);
        colv[(size_t)ci * ET_ + pos] = s;
        valv[(size_t)ci * ET_ + pos] = degS[s] * ew[e] * degS[t];
    }
}

// ------------------------------------------------ W transpose + pack ----
// Wh[l][k][n] fp32 -> WTpack[l][n][512] bf16: [k]=hi, [256+k]=lo.
__global__ __launch_bounds__(256) void wsplit_kernel(
    const float* __restrict__ Wh, __hip_bfloat16* __restrict__ WTpack)
{
    const int idx = blockIdx.x * 256 + threadIdx.x;
    if (idx >= (L_ - 1) * H_ * H_) return;
    const int l = idx >> 16, rem = idx & 65535;
    const int n = rem >> 8, k = rem & 255;
    const float w = Wh[(size_t)l * H_ * H_ + (size_t)k * H_ + n];
    const __hip_bfloat16 hi = __float2bfloat16(w);
    const __hip_bfloat16 lo = __float2bfloat16(w - __bfloat162float(hi));
    __hip_bfloat16* base = WTpack + ((size_t)(l * H_ + n)) * KP_;
    base[k] = hi; base[H_ + k] = lo;
}

// ---------------------------------------------------- layer-0 transform ----
__global__ __launch_bounds__(256) void xw0_kernel(
    const float* __restrict__ hx, const float* __restrict__ ax,
    const float* __restrict__ W0, int inst0, float* __restrict__ h0)
{
    const int ci = blockIdx.x >> 5;
    const int n0 = (blockIdx.x & 31) << 4;
    const int c  = threadIdx.x;
    const int b  = inst0 + ci;
    const int g  = (b < G_) ? b : b - G_;
    const float w0 = W0[c], w1 = W0[H_ + c], w2 = W0[2 * H_ + c], w3 = W0[3 * H_ + c];
    const float* x = ((b < G_) ? hx : ax) + ((size_t)g * N_ + n0) * FIN;
    float* o = h0 + (((size_t)ci * N_ + n0) << 8) + c;
#pragma unroll
    for (int i = 0; i < 16; ++i) {
        const float4 xv = *(const float4*)&x[i * 4];
        float acc = xv.x * w0;
        acc = fmaf(xv.y, w1, acc);
        acc = fmaf(xv.z, w2, acc);
        acc = fmaf(xv.w, w3, acc);
        o[(size_t)i << 8] = acc;
    }
}

// ----------------------------------------------------- packed MFMA GEMM ----
// C[M,256] = split-GEMM over 24 virtual BK=32 steps:
//   steps 0-7 : A hi x W hi ; 8-15 : A lo x W hi ; 16-23 : A hi x W lo.
// BM=BN=128, 256 thr (2x2 waves), double-buffered 16KB LDS.
__global__ __launch_bounds__(256, 3) void gemm_mfma_kernel(
    const short* __restrict__ A,     // [M][512] bf16 bits [hi|lo]
    const short* __restrict__ B,     // [256][512] bf16 bits [Whi|Wlo]
    float* __restrict__ Cout)        // [M][256]
{
    __shared__ short lA[2][4096];    // [buf][(kb*128+row)*8+j] : 8 KiB/buf
    __shared__ short lB[2][4096];

    const int tid  = threadIdx.x;
    const int w    = xcd_chunk_swizzle(blockIdx.x, gridDim.x);
    const int m0   = (w >> 1) * 128;
    const int n0   = (w & 1) * 128;
    const int lane = tid & 63;
    const int wave = tid >> 6;
    const int wm   = (wave >> 1) * 64;
    const int wn   = (wave & 1) * 64;
    const int l15  = lane & 15;
    const int kb4  = lane >> 4;

    f32x4 acc[4][4];
#pragma unroll
    for (int i = 0; i < 4; ++i)
#pragma unroll
        for (int j = 0; j < 4; ++j) acc[i][j] = (f32x4)0.f;

#define AKOF(st) ((st) < 8 ? (st) * 32 : (st) < 16 ? ((st) - 8) * 32 + 256 : ((st) - 16) * 32)
#define BKOF(st) ((st) < 8 ? (st) * 32 : (st) < 16 ? ((st) - 8) * 32 : ((st) - 16) * 32 + 256)

#define STG(buf, ak, bk) do { \
    _Pragma("unroll") for (int call = 0; call < 2; ++call) { \
        const int c = call * 256 + tid; \
        const int row = c & 127, kb = c >> 7; \
        gload_lds16(A + (size_t)(m0 + row) * KP_ + (ak) + (kb << 3), \
                    &lA[buf][(c & ~63) << 3]); \
        gload_lds16(B + (size_t)(n0 + row) * KP_ + (bk) + (kb << 3), \
                    &lB[buf][(c & ~63) << 3]); \
    } } while (0)

#define COMP(buf) do { \
    bf16x8 av[4]; \
    _Pragma("unroll") for (int mf = 0; mf < 4; ++mf) \
        av[mf] = *(const bf16x8*)&lA[buf][(kb4 * 128 + wm + mf * 16 + l15) << 3]; \
    _Pragma("unroll") for (int nf = 0; nf < 4; ++nf) { \
        const bf16x8 bv = *(const bf16x8*)&lB[buf][(kb4 * 128 + wn + nf * 16 + l15) << 3]; \
        _Pragma("unroll") for (int mf = 0; mf < 4; ++mf) \
            acc[mf][nf] = __builtin_amdgcn_mfma_f32_16x16x32_bf16(av[mf], bv, acc[mf][nf], 0, 0, 0); \
    } } while (0)

    STG(0, 0, 0);
    __syncthreads();
#pragma unroll
    for (int st = 0; st < 23; ++st) {
        STG((st + 1) & 1, AKOF(st + 1), BKOF(st + 1));  // async next K-step
        COMP(st & 1);                                   // compute current
        __syncthreads();                                // vmcnt+lgkm drained
    }
    COMP(1);

#pragma unroll
    for (int mf = 0; mf < 4; ++mf) {
        const int r0 = m0 + wm + mf * 16 + (kb4 << 2);
#pragma unroll
        for (int nf = 0; nf < 4; ++nf) {
            const int col = n0 + wn + nf * 16 + l15;
            const f32x4 v = acc[mf][nf];
#pragma unroll
            for (int j = 0; j < 4; ++j)
                Cout[((size_t)(r0 + j) << 8) + col] = v[j];
        }
    }
#undef STG
#undef COMP
#undef AKOF
#undef BKOF
}

// ---------------------------------------------------------- aggregation ----
// block = (instance, 64-ch chunk), 1024 thr (16 waves x 32 rows).
// h[:, chunk] staged in 128 KiB LDS. Edge data read with wave-UNIFORM
// indices (-> s_load), weight enters v_fmac as SGPR operand; x8 unroll,
// 4 accumulators. Self-loop is in CSR. Output: packed bf16 [hi | lo].
__global__ __launch_bounds__(1024, 4) void agg_kernel(
    const float* __restrict__ h, const int* __restrict__ colv,
    const float* __restrict__ valv, const int* __restrict__ rowptr,
    const float* __restrict__ bias, __hip_bfloat16* __restrict__ xpack)
{
    __shared__ float hs[N_ * 64];   // 128 KiB: hs[n][c]
    const int w    = xcd_chunk_swizzle(blockIdx.x, gridDim.x);
    const int ci   = w >> 2;
    const int c0   = (w & 3) << 6;
    const int tid  = threadIdx.x;
    const int lane = tid & 63;
    const int wv   = tid >> 6;

    const float* hb = h + (size_t)ci * N_ * H_;
#pragma unroll
    for (int it = 0; it < 8; ++it) {            // 8192 16B chunks / 1024 thr
        const int i  = it * 1024 + tid;
        const int n  = i >> 4;
        const int c4 = (i & 15) << 2;
        gload_lds16(hb + (size_t)n * H_ + c0 + c4, &hs[(i & ~63) << 2]);
    }
    __syncthreads();

    const int*   rp = rowptr + (size_t)ci * (N_ + 1);
    const int*   cv = colv + (size_t)ci * ET_;
    const float* vv = valv + (size_t)ci * ET_;
    const float bval = bias[c0 + lane];

    for (int t = wv * 32; t < wv * 32 + 32; ++t) {
        const int r0 = rp[t], r1 = rp[t + 1];
        float a0 = 0.f, a1 = 0.f, a2 = 0.f, a3 = 0.f;
        int e = r0;
        for (; e + 8 <= r1; e += 8) {
            const int   s0 = cv[e + 0], s1 = cv[e + 1], s2 = cv[e + 2], s3 = cv[e + 3];
            const int   s4 = cv[e + 4], s5 = cv[e + 5], s6 = cv[e + 6], s7 = cv[e + 7];
            const float w0 = vv[e + 0], w1 = vv[e + 1], w2 = vv[e + 2], w3 = vv[e + 3];
            const float w4 = vv[e + 4], w5 = vv[e + 5], w6 = vv[e + 6], w7 = vv[e + 7];
            a0 = fmaf(w0, hs[s0 * 64 + lane], a0);
            a1 = fmaf(w1, hs[s1 * 64 + lane], a1);
            a2 = fmaf(w2, hs[s2 * 64 + lane], a2);
            a3 = fmaf(w3, hs[s3 * 64 + lane], a3);
            a0 = fmaf(w4, hs[s4 * 64 + lane], a0);
            a1 = fmaf(w5, hs[s5 * 64 + lane], a1);
            a2 = fmaf(w6, hs[s6 * 64 + lane], a2);
            a3 = fmaf(w7, hs[s7 * 64 + lane], a3);
        }
        for (; e < r1; ++e)
            a0 = fmaf(vv[e], hs[cv[e] * 64 + lane], a0);

        const float o = fmaxf(a0 + a1 + a2 + a3 + bval, 0.f);
        const __hip_bfloat16 hi = __float2bfloat16(o);
        const __hip_bfloat16 lo = __float2bfloat16(o - __bfloat162float(hi));
        __hip_bfloat16* xr = xpack + ((size_t)ci * N_ + t) * KP_ + c0 + lane;
        xr[0] = hi; xr[H_] = lo;
    }
}

// ----------------------------------------------------------------- pool ----
__global__ __launch_bounds__(256) void pool_kernel(
    const __hip_bfloat16* __restrict__ xpack, int inst0, float* __restrict__ pooled)
{
    const int ci = blockIdx.x;
    const int c  = threadIdx.x;
    const __hip_bfloat16* xp = xpack + (size_t)ci * N_ * KP_;
    float a0 = 0.f, a1 = 0.f, a2 = 0.f, a3 = 0.f;
    for (int n = 0; n < N_; n += 4) {
        a0 += __bfloat162float(xp[(size_t)(n + 0) * KP_ + c]) + __bfloat162float(xp[(size_t)(n + 0) * KP_ + H_ + c]);
        a1 += __bfloat162float(xp[(size_t)(n + 1) * KP_ + c]) + __bfloat162float(xp[(size_t)(n + 1) * KP_ + H_ + c]);
        a2 += __bfloat162float(xp[(size_t)(n + 2) * KP_ + c]) + __bfloat162float(xp[(size_t)(n + 2) * KP_ + H_ + c]);
        a3 += __bfloat162float(xp[(size_t)(n + 3) * KP_ + c]) + __bfloat162float(xp[(size_t)(n + 3) * KP_ + H_ + c]);
    }
    pooled[(size_t)(inst0 + ci) * H_ + c] = (a0 + a1 + a2 + a3) * (1.0f / N_);
}

// ------------------------------------------------------------------- fc ----
__global__ __launch_bounds__(256) void fc_kernel(
    const float* __restrict__ pooled, const float* __restrict__ hf,
    const float* __restrict__ af, const float* __restrict__ fcW,
    const float* __restrict__ fcb, float* __restrict__ outp)
{
    const int idx = blockIdx.x * 256 + threadIdx.x;
    if (idx >= G_ * C_) return;
    const int gi = idx / C_;
    const int c  = idx % C_;
    float acc = fcb[c];
    const float* ph = pooled + (size_t)gi * H_;
    const float* pa = pooled + (size_t)(G_ + gi) * H_;
    for (int j = 0; j < H_; ++j) acc += ph[j] * fcW[j * C_ + c];
    for (int j = 0; j < FG; ++j) acc += hf[gi * FG + j] * fcW[(H_ + j) * C_ + c];
    for (int j = 0; j < H_; ++j) acc += pa[j] * fcW[(H_ + FG + j) * C_ + c];
    for (int j = 0; j < FG; ++j) acc += af[gi * FG + j] * fcW[(H_ + FG + H_ + j) * C_ + c];
    outp[idx] = acc;
}

// ----------------------------------------------------------------- host ----
static inline size_t align_up(size_t v, size_t a) { return (v + a - 1) & ~(a - 1); }

extern "C" void kernel_launch(void* const* d_in, const int* in_sizes, int n_in,
                              void* d_out, int out_size, void* d_ws, size_t ws_size,
                              hipStream_t stream)
{
    const float* hx  = (const float*)d_in[0];
    const float* ax  = (const float*)d_in[1];
    const int*   hei = (const int*)d_in[2];
    const int*   aei = (const int*)d_in[3];
    const float* hew = (const float*)d_in[4];
    const float* aew = (const float*)d_in[5];
    const float* hf  = (const float*)d_in[6];
    const float* af  = (const float*)d_in[7];
    const float* W0  = (const float*)d_in[8];
    const float* Wh  = (const float*)d_in[9];
    const float* bs  = (const float*)d_in[10];
    const float* fcW = (const float*)d_in[11];
    const float* fcb = (const float*)d_in[12];
    float* outp = (float*)d_out;

    const size_t pooled_b = align_up((size_t)B_ * H_ * sizeof(float), 256);
    const size_t wtp_b    = align_up((size_t)(L_ - 1) * H_ * KP_ * sizeof(__hip_bfloat16), 256);
    const size_t col_b  = align_up((size_t)ET_ * sizeof(int), 256);
    const size_t val_b  = align_up((size_t)ET_ * sizeof(float), 256);
    const size_t rp_b   = align_up((size_t)(N_ + 1) * sizeof(int), 256);
    const size_t h_b    = align_up((size_t)N_ * H_ * sizeof(float), 256);
    const size_t xp_b   = align_up((size_t)N_ * KP_ * sizeof(__hip_bfloat16), 256);
    const size_t per_inst = col_b + val_b + rp_b + h_b + xp_b;
    const size_t fixed = pooled_b + wtp_b;

    int CB = (int)((ws_size > fixed) ? (ws_size - fixed) / per_inst : 0);
    if (CB < 1) CB = 1;
    if (CB > B_) CB = B_;

    char* p = (char*)d_ws;
    float* pooled = (float*)p;                   p += pooled_b;
    __hip_bfloat16* WTpack = (__hip_bfloat16*)p; p += wtp_b;
    int*   colv = (int*)p;                       p += (size_t)CB * col_b;
    float* valv = (float*)p;                     p += (size_t)CB * val_b;
    int*   rowptr = (int*)p;                     p += (size_t)CB * rp_b;
    float* hbuf = (float*)p;                     p += (size_t)CB * h_b;
    __hip_bfloat16* xpack = (__hip_bfloat16*)p;

    wsplit_kernel<<<((L_ - 1) * H_ * H_ + 255) / 256, 256, 0, stream>>>(Wh, WTpack);

    for (int i0 = 0; i0 < B_; i0 += CB) {
        const int cb = (B_ - i0 < CB) ? (B_ - i0) : CB;

        prep_kernel<<<cb, 256, 0, stream>>>(hei, aei, hew, aew, i0, colv, valv, rowptr);
        xw0_kernel<<<cb * 32, 256, 0, stream>>>(hx, ax, W0, i0, hbuf);

        for (int l = 0; l < L_; ++l) {
            if (l > 0) {
                gemm_mfma_kernel<<<cb * 8, 256, 0, stream>>>(
                    (const short*)xpack,
                    (const short*)(WTpack + (size_t)(l - 1) * H_ * KP_),
                    hbuf);
            }
            agg_kernel<<<cb * 4, 1024, 0, stream>>>(
                hbuf, colv, valv, rowptr, bs + (size_t)l * H_, xpack);
        }
        pool_kernel<<<cb, 256, 0, stream>>>(xpack, i0, pooled);
    }

    fc_kernel<<<(G_ * C_ + 255) / 256, 256, 0, stream>>>(pooled, hf, af, fcW, fcb, outp);
}